// Round 12
// baseline (318.329 us; speedup 1.0000x reference)
//
#include <hip/hip_runtime.h>
#include <hip/hip_bf16.h>
#include <stdint.h>

#define N_NODES 20000
#define N_EDGES 160000
#define D 512
#define M_PAD 20096   /* 157 * 128 */
#define NT 16         /* K-steps of 32 over K=512 */

typedef __attribute__((ext_vector_type(8))) short bf16x8;
typedef __attribute__((ext_vector_type(4))) float f32x4;
typedef __attribute__((ext_vector_type(2))) float f32x2;

__device__ __forceinline__ unsigned short f2bf(float f) {
    unsigned u = __float_as_uint(f);
    u += 0x7fffu + ((u >> 16) & 1u);
    return (unsigned short)(u >> 16);
}
__device__ __forceinline__ float bflo(unsigned u) { return __uint_as_float(u << 16); }
__device__ __forceinline__ float bfhi(unsigned u) { return __uint_as_float(u & 0xffff0000u); }
__device__ __forceinline__ unsigned pack2(float a, float b) {
    return (unsigned)f2bf(a) | ((unsigned)f2bf(b) << 16);
}

// ---------- fused prologue: cvt_x + weight prep + zero(cnt), block-range dispatch ----------
#define CVT_BLOCKS  (M_PAD * D / 8 / 256)            /* 5024 */
#define PREP_BLOCKS (3 * 1024 * 512 / 4 / 256)       /* 1536 */
#define ZERO_BLOCKS ((N_NODES + 255) / 256)          /* 79  */

__global__ void prologue_kernel(
    const float* __restrict__ x, unsigned short* __restrict__ xb,
    const float* __restrict__ wr1, const float* __restrict__ wo1, const float* __restrict__ wl1,
    const float* __restrict__ br1, const float* __restrict__ bl1,
    const float* __restrict__ wr2, const float* __restrict__ wo2, const float* __restrict__ wl2,
    const float* __restrict__ br2, const float* __restrict__ bl2,
    const float* __restrict__ wr3, const float* __restrict__ wo3, const float* __restrict__ wl3,
    const float* __restrict__ br3, const float* __restrict__ bl3,
    unsigned short* __restrict__ wcat,   // [3][1024][512]
    float* __restrict__ bias,            // [3][512]
    int* __restrict__ cnt) {
    int b = blockIdx.x;
    if (b < CVT_BLOCKS) {
        long t = (long)b * 256 + threadIdx.x;   // one thread per 8 elems
        long base = t * 8;
        int row = (int)(base >> 9);
        uint4 o;
        if (row < N_NODES) {
            float4 f0 = *(const float4*)(x + base);
            float4 f1 = *(const float4*)(x + base + 4);
            o.x = pack2(f0.x, f0.y);
            o.y = pack2(f0.z, f0.w);
            o.z = pack2(f1.x, f1.y);
            o.w = pack2(f1.z, f1.w);
        } else {
            o = make_uint4(0u, 0u, 0u, 0u);
        }
        *(uint4*)(xb + base) = o;
        return;
    }
    b -= CVT_BLOCKS;
    if (b < PREP_BLOCKS) {
        int gid = b * 256 + threadIdx.x;   // 1 thread per 4 elems
        const float* wrel[3]  = {wr1, wr2, wr3};
        const float* wroot[3] = {wo1, wo2, wo3};
        const float* wlin[3]  = {wl1, wl2, wl3};
        int layer = gid / (1024 * 512 / 4);
        int rem   = gid % (1024 * 512 / 4);
        int base  = rem * 4;                 // elem index within [1024][512]
        int row = base >> 9;
        int col = base & 511;
        float4 v;
        if (row < 512) {
            v = *(const float4*)(wrel[layer] + row * 512 + col);
        } else {
            float4 a = *(const float4*)(wroot[layer] + (row - 512) * 512 + col);
            float4 bb = *(const float4*)(wlin[layer] + (row - 512) * 512 + col);
            v = make_float4(a.x + bb.x, a.y + bb.y, a.z + bb.z, a.w + bb.w);
        }
        uint2 o;
        o.x = pack2(v.x, v.y);
        o.y = pack2(v.z, v.w);
        *(uint2*)(wcat + (long)layer * 1024 * 512 + base) = o;
        if (gid < 3 * 512) {
            const float* brel[3] = {br1, br2, br3};
            const float* blin[3] = {bl1, bl2, bl3};
            int ly = gid / 512, c = gid % 512;
            bias[gid] = brel[ly][c] + blin[ly][c];
        }
        return;
    }
    b -= PREP_BLOCKS;
    {
        int i = b * 256 + threadIdx.x;
        if (i < N_NODES) cnt[i] = 0;
    }
}

// ---------- CSR build ----------
__global__ void count_kernel(const int* __restrict__ dst, int* __restrict__ cnt) {
    int e = blockIdx.x * 256 + threadIdx.x;
    if (e < N_EDGES) atomicAdd(&cnt[dst[e]], 1);
}

__global__ void scan_kernel(const int* __restrict__ cnt, int* __restrict__ rowptr,
                            int* __restrict__ cursor) {
    __shared__ int sc[1024];
    int t = threadIdx.x;
    const int CH = 20;
    int base = t * CH;
    int s = 0;
    for (int i = 0; i < CH; i++) {
        int idx = base + i;
        if (idx < N_NODES) s += cnt[idx];
    }
    sc[t] = s;
    __syncthreads();
    for (int off = 1; off < 1024; off <<= 1) {
        int v = (t >= off) ? sc[t - off] : 0;
        __syncthreads();
        sc[t] += v;
        __syncthreads();
    }
    int run = sc[t] - s;
    for (int i = 0; i < CH; i++) {
        int idx = base + i;
        if (idx < N_NODES) {
            rowptr[idx] = run;
            cursor[idx] = run;
            run += cnt[idx];
        }
    }
    if (t == 1023) rowptr[N_NODES] = sc[1023];
}

__global__ void fill_kernel(const int* __restrict__ src, const int* __restrict__ dst,
                            int* __restrict__ cursor, int* __restrict__ esrc) {
    int e = blockIdx.x * 256 + threadIdx.x;
    if (e < N_EDGES) {
        int p = atomicAdd(&cursor[dst[e]], 1);
        esrc[p] = src[e];
    }
}

// ---------- GEMM: H[M,1024] = X[M,512] @ Wcat^T ; split stores H1/H2 bf16 ----------
// r7-proven config (survivor of 4 structural challenges): 128x128 tile, BK=32,
// 256 threads (4 waves), TRIPLE-buffered LDS with counted vmcnt (T4).
// LDS swizzle (rule #21): slot' = slot ^ ((row>>1)&3) within each row's 64B
// line; staging source chunk = (l&3)^((l>>3)&3) keeps 64B-coalesced segments.
// DO NOT: raise min-waves (r5 spill), widen tile (r8 occupancy), or load B
// per-lane from global (r9 uncoalesced 1KB-stride).
__global__ __launch_bounds__(256, 4) void gemm_kernel(
    const unsigned short* __restrict__ A,      // [M_PAD][512] bf16
    const unsigned short* __restrict__ Wcat,   // [1024][512] bf16
    unsigned short* __restrict__ H1,           // [N_NODES][512]
    unsigned short* __restrict__ H2) {         // [N_NODES][512]
    __shared__ short Alds[3][128 * 32];
    __shared__ short Blds[3][128 * 32];
    int t = threadIdx.x;
    int wave = t >> 6, lane = t & 63;
    int s = blockIdx.x;
    int orig = (s & 7) * 157 + (s >> 3);       // bijective XCD swizzle (1256 = 8*157)
    int tm0 = (orig >> 3) * 128;
    int tn0 = (orig & 7) * 128;
    int wr = wave >> 1, wc = wave & 1;
    int lr = lane & 15, lg = lane >> 4;
    int q   = lane >> 2;                        // staging: row within 16-row group
    int cc  = (lane & 3) ^ ((lane >> 3) & 3);   // staging: global 16B-chunk (inv-swizzle)

    const unsigned short* Abase = A + (long)tm0 * D;
    const unsigned short* Bbase = Wcat + (long)tn0 * D;

    f32x4 acc[4][4];
#pragma unroll
    for (int i = 0; i < 4; i++)
#pragma unroll
        for (int j = 0; j < 4; j++) acc[i][j] = (f32x4){0.f, 0.f, 0.f, 0.f};

    auto stage = [&](int buf, int kt) {
        int kl = kt * 32;
#pragma unroll
        for (int i = 0; i < 2; i++) {
            int g = i * 4 + wave;              // 16-row group index 0..7
            __builtin_amdgcn_global_load_lds(
                (const __attribute__((address_space(1))) unsigned int*)(Abase + (long)(g * 16 + q) * D + kl + cc * 8),
                (__attribute__((address_space(3))) unsigned int*)&Alds[buf][g * 512],
                16, 0, 0);
            __builtin_amdgcn_global_load_lds(
                (const __attribute__((address_space(1))) unsigned int*)(Bbase + (long)(g * 16 + q) * D + kl + cc * 8),
                (__attribute__((address_space(3))) unsigned int*)&Blds[buf][g * 512],
                16, 0, 0);
        }
    };

    int swz = ((lr >> 1) & 3);   // read-side slot swizzle = (row>>1)&3 for fragment rows
    stage(0, 0);
    stage(1, 1);
    for (int kt = 0; kt < NT; ++kt) {
        // wait my stage(kt) retired: stage(kt+1) (4 loads) may remain in flight
        if (kt < NT - 1) asm volatile("s_waitcnt vmcnt(4)" ::: "memory");
        else             asm volatile("s_waitcnt vmcnt(0)" ::: "memory");
        __builtin_amdgcn_s_barrier();          // all waves: stage(kt) done, k-1 reads done
        __builtin_amdgcn_sched_barrier(0);     // no ds_read hoisting above the barrier
        if (kt + 2 < NT) stage((kt + 2) % 3, kt + 2);   // overwrites buf (kt-1)%3: safe

        int cur = kt % 3;
        bf16x8 af[4], wf[4];
#pragma unroll
        for (int i = 0; i < 4; i++)
            af[i] = *(const bf16x8*)&Alds[cur][(wr * 64 + i * 16 + lr) * 32 + (lg ^ swz) * 8];
#pragma unroll
        for (int j = 0; j < 4; j++)
            wf[j] = *(const bf16x8*)&Blds[cur][(wc * 64 + j * 16 + lr) * 32 + (lg ^ swz) * 8];
#pragma unroll
        for (int i = 0; i < 4; i++)
#pragma unroll
            for (int j = 0; j < 4; j++)
                acc[i][j] = __builtin_amdgcn_mfma_f32_16x16x32_bf16(af[i], wf[j], acc[i][j], 0, 0, 0);
    }

    // epilogue: split store (bias applied post-aggregation)
    bool hi = (tn0 >= 512);
    unsigned short* Hout = hi ? H2 : H1;
    int ncol0 = tn0 - (hi ? 512 : 0);
#pragma unroll
    for (int i = 0; i < 4; i++) {
        int mb = tm0 + wr * 64 + i * 16 + lg * 4;
#pragma unroll
        for (int j = 0; j < 4; j++) {
            int n = ncol0 + wc * 64 + j * 16 + lr;
#pragma unroll
            for (int r = 0; r < 4; r++) {
                int m = mb + r;
                if (m < N_NODES) Hout[(long)m * D + n] = f2bf(acc[i][j][r]);
            }
        }
    }
}

// ---------- fused aggregate + skip + bias (+relu): Y = agg(H1) + H2 + bias ----------
// COLUMN-SLICED (r12): 8 slices x 64 cols. Per-slice H1 working set =
// 20000*64*2B = 2.56MB < 4MB L2/XCD -> gather becomes L2-resident instead of
// L3/HBM (was ~6.2 TB/s effective). Slices write disjoint columns: no sync.
// Slice-major blockIdx keeps one slice hot as the dispatch wavefront advances.
// Wave = 2 nodes x 32 lanes; per-edge read = 32 lanes x 4B = 128B contiguous.
#define NSLICE 8
#define SLICE_COLS 64
#define NODES_PER_BLOCK 8          /* 4 waves x 2 nodes */
#define BLOCKS_PER_SLICE (M_PAD / NODES_PER_BLOCK)   /* 2512 */

#define ACC2(u)  do { a0 += bflo(u); a1 += bfhi(u); } while (0)

template <bool RELU, bool F32OUT>
__global__ __launch_bounds__(256, 8) void agg_kernel(
    const unsigned short* __restrict__ H1, const unsigned short* __restrict__ H2,
    const int* __restrict__ rowptr, const int* __restrict__ esrc,
    const float* __restrict__ bias,
    unsigned short* __restrict__ xn, float* __restrict__ fout) {
    int slice = blockIdx.x / BLOCKS_PER_SLICE;
    int nb    = blockIdx.x % BLOCKS_PER_SLICE;
    int wave = threadIdx.x >> 6;
    int lane = threadIdx.x & 63;
    int n = nb * NODES_PER_BLOCK + wave * 2 + (lane >> 5);
    int colpair = lane & 31;                       // 2 cols per lane
    long cofs = slice * SLICE_COLS + colpair * 2;  // element offset within row
    if (n >= N_NODES) {
        if (!F32OUT && n < M_PAD)
            *(unsigned*)(xn + (long)n * D + cofs) = 0u;
        return;
    }
    int s = rowptr[n], e = rowptr[n + 1];
    unsigned h2 = *(const unsigned*)(H2 + (long)n * D + cofs);
    f32x2 b01 = *(const f32x2*)(bias + cofs);
    float a0 = 0.f, a1 = 0.f;
    const unsigned short* H1c = H1 + cofs;
    int i = s;
    for (; i + 8 <= e; i += 8) {    // 8 gathers in flight per wave
        int s0 = esrc[i], s1 = esrc[i + 1], s2 = esrc[i + 2], s3 = esrc[i + 3];
        int s4 = esrc[i + 4], s5 = esrc[i + 5], s6 = esrc[i + 6], s7 = esrc[i + 7];
        unsigned u0 = *(const unsigned*)(H1c + (long)s0 * D);
        unsigned u1 = *(const unsigned*)(H1c + (long)s1 * D);
        unsigned u2 = *(const unsigned*)(H1c + (long)s2 * D);
        unsigned u3 = *(const unsigned*)(H1c + (long)s3 * D);
        unsigned u4 = *(const unsigned*)(H1c + (long)s4 * D);
        unsigned u5 = *(const unsigned*)(H1c + (long)s5 * D);
        unsigned u6 = *(const unsigned*)(H1c + (long)s6 * D);
        unsigned u7 = *(const unsigned*)(H1c + (long)s7 * D);
        ACC2(u0); ACC2(u1); ACC2(u2); ACC2(u3);
        ACC2(u4); ACC2(u5); ACC2(u6); ACC2(u7);
    }
    for (; i < e; i++) {
        unsigned u = *(const unsigned*)(H1c + (long)esrc[i] * D);
        ACC2(u);
    }
    float o0 = a0 + bflo(h2) + b01.x;
    float o1 = a1 + bfhi(h2) + b01.y;
    if (RELU) {
        o0 = o0 > 0.f ? o0 : 0.f;
        o1 = o1 > 0.f ? o1 : 0.f;
    }
    if (F32OUT) {
        // non-temporal: d_out never re-read; don't evict H1 from L2
        float* dst = fout + (long)n * D + cofs;
        f32x2 o = {o0, o1};
        __builtin_nontemporal_store(o, (f32x2*)dst);
    } else {
        *(unsigned*)(xn + (long)n * D + cofs) = pack2(o0, o1);
    }
}

extern "C" void kernel_launch(void* const* d_in, const int* in_sizes, int n_in,
                              void* d_out, int out_size, void* d_ws, size_t ws_size,
                              hipStream_t stream) {
    const float* x = (const float*)d_in[0];
    const int* ei = (const int*)d_in[1];
    const int* esrc_in = ei;             // row 0: src
    const int* edst_in = ei + N_EDGES;   // row 1: dst

    char* p = (char*)d_ws;
    size_t off = 0;
    auto alloc = [&](size_t bytes) -> char* {
        char* r = p + off;
        off = (off + bytes + 255) & ~(size_t)255;
        return r;
    };
    unsigned short* xA   = (unsigned short*)alloc((size_t)M_PAD * D * 2);
    unsigned short* xB   = (unsigned short*)alloc((size_t)M_PAD * D * 2);
    unsigned short* H1   = (unsigned short*)alloc((size_t)N_NODES * D * 2);
    unsigned short* H2   = (unsigned short*)alloc((size_t)N_NODES * D * 2);
    unsigned short* wcat = (unsigned short*)alloc((size_t)3 * 1024 * 512 * 2);
    float* biasb = (float*)alloc(3 * 512 * 4);
    int* cnt    = (int*)alloc(N_NODES * 4);
    int* rowptr = (int*)alloc((N_NODES + 1) * 4);
    int* cursor = (int*)alloc(N_NODES * 4);
    int* esrc   = (int*)alloc(N_EDGES * 4);

    prologue_kernel<<<CVT_BLOCKS + PREP_BLOCKS + ZERO_BLOCKS, 256, 0, stream>>>(
        x, xA,
        (const float*)d_in[2], (const float*)d_in[4], (const float*)d_in[5],
        (const float*)d_in[3], (const float*)d_in[6],
        (const float*)d_in[7], (const float*)d_in[9], (const float*)d_in[10],
        (const float*)d_in[8], (const float*)d_in[11],
        (const float*)d_in[12], (const float*)d_in[14], (const float*)d_in[15],
        (const float*)d_in[13], (const float*)d_in[16],
        wcat, biasb, cnt);
    count_kernel<<<(N_EDGES + 255) / 256, 256, 0, stream>>>(edst_in, cnt);
    scan_kernel<<<1, 1024, 0, stream>>>(cnt, rowptr, cursor);
    fill_kernel<<<(N_EDGES + 255) / 256, 256, 0, stream>>>(esrc_in, edst_in, cursor, esrc);

    unsigned short* xc = xA;
    unsigned short* xn = xB;
    for (int l = 0; l < 3; l++) {
        gemm_kernel<<<157 * 8, 256, 0, stream>>>(xc, wcat + (long)l * 1024 * 512, H1, H2);
        if (l < 2)
            agg_kernel<true, false><<<NSLICE * BLOCKS_PER_SLICE, 256, 0, stream>>>(
                H1, H2, rowptr, esrc, biasb + l * 512, xn, nullptr);
        else
            agg_kernel<false, true><<<NSLICE * BLOCKS_PER_SLICE, 256, 0, stream>>>(
                H1, H2, rowptr, esrc, biasb + l * 512, nullptr, (float*)d_out);
        unsigned short* tmp = xc;
        xc = xn;
        xn = tmp;
    }
}

// Round 13
// 248.635 us; speedup vs baseline: 1.2803x; 1.2803x over previous
//
#include <hip/hip_runtime.h>
#include <hip/hip_bf16.h>
#include <stdint.h>

#define N_NODES 20000
#define N_EDGES 160000
#define D 512
#define M_PAD 20096   /* 157 * 128 */
#define NT 16         /* K-steps of 32 over K=512 */

typedef __attribute__((ext_vector_type(8))) short bf16x8;
typedef __attribute__((ext_vector_type(4))) float f32x4;

__device__ __forceinline__ unsigned short f2bf(float f) {
    unsigned u = __float_as_uint(f);
    u += 0x7fffu + ((u >> 16) & 1u);
    return (unsigned short)(u >> 16);
}
__device__ __forceinline__ float bflo(unsigned u) { return __uint_as_float(u << 16); }
__device__ __forceinline__ float bfhi(unsigned u) { return __uint_as_float(u & 0xffff0000u); }
__device__ __forceinline__ unsigned pack2(float a, float b) {
    return (unsigned)f2bf(a) | ((unsigned)f2bf(b) << 16);
}

// ---------- fused prologue: cvt_x + weight prep + zero(cnt), block-range dispatch ----------
#define CVT_BLOCKS  (M_PAD * D / 8 / 256)            /* 5024 */
#define PREP_BLOCKS (3 * 1024 * 512 / 4 / 256)       /* 1536 */
#define ZERO_BLOCKS ((N_NODES + 255) / 256)          /* 79  */

__global__ void prologue_kernel(
    const float* __restrict__ x, unsigned short* __restrict__ xb,
    const float* __restrict__ wr1, const float* __restrict__ wo1, const float* __restrict__ wl1,
    const float* __restrict__ br1, const float* __restrict__ bl1,
    const float* __restrict__ wr2, const float* __restrict__ wo2, const float* __restrict__ wl2,
    const float* __restrict__ br2, const float* __restrict__ bl2,
    const float* __restrict__ wr3, const float* __restrict__ wo3, const float* __restrict__ wl3,
    const float* __restrict__ br3, const float* __restrict__ bl3,
    unsigned short* __restrict__ wcat,   // [3][1024][512]
    float* __restrict__ bias,            // [3][512]
    int* __restrict__ cnt) {
    int b = blockIdx.x;
    if (b < CVT_BLOCKS) {
        long t = (long)b * 256 + threadIdx.x;   // one thread per 8 elems
        long base = t * 8;
        int row = (int)(base >> 9);
        uint4 o;
        if (row < N_NODES) {
            float4 f0 = *(const float4*)(x + base);
            float4 f1 = *(const float4*)(x + base + 4);
            o.x = pack2(f0.x, f0.y);
            o.y = pack2(f0.z, f0.w);
            o.z = pack2(f1.x, f1.y);
            o.w = pack2(f1.z, f1.w);
        } else {
            o = make_uint4(0u, 0u, 0u, 0u);
        }
        *(uint4*)(xb + base) = o;
        return;
    }
    b -= CVT_BLOCKS;
    if (b < PREP_BLOCKS) {
        int gid = b * 256 + threadIdx.x;   // 1 thread per 4 elems
        const float* wrel[3]  = {wr1, wr2, wr3};
        const float* wroot[3] = {wo1, wo2, wo3};
        const float* wlin[3]  = {wl1, wl2, wl3};
        int layer = gid / (1024 * 512 / 4);
        int rem   = gid % (1024 * 512 / 4);
        int base  = rem * 4;                 // elem index within [1024][512]
        int row = base >> 9;
        int col = base & 511;
        float4 v;
        if (row < 512) {
            v = *(const float4*)(wrel[layer] + row * 512 + col);
        } else {
            float4 a = *(const float4*)(wroot[layer] + (row - 512) * 512 + col);
            float4 bb = *(const float4*)(wlin[layer] + (row - 512) * 512 + col);
            v = make_float4(a.x + bb.x, a.y + bb.y, a.z + bb.z, a.w + bb.w);
        }
        uint2 o;
        o.x = pack2(v.x, v.y);
        o.y = pack2(v.z, v.w);
        *(uint2*)(wcat + (long)layer * 1024 * 512 + base) = o;
        if (gid < 3 * 512) {
            const float* brel[3] = {br1, br2, br3};
            const float* blin[3] = {bl1, bl2, bl3};
            int ly = gid / 512, c = gid % 512;
            bias[gid] = brel[ly][c] + blin[ly][c];
        }
        return;
    }
    b -= PREP_BLOCKS;
    {
        int i = b * 256 + threadIdx.x;
        if (i < N_NODES) cnt[i] = 0;
    }
}

// ---------- CSR build ----------
__global__ void count_kernel(const int* __restrict__ dst, int* __restrict__ cnt) {
    int e = blockIdx.x * 256 + threadIdx.x;
    if (e < N_EDGES) atomicAdd(&cnt[dst[e]], 1);
}

__global__ void scan_kernel(const int* __restrict__ cnt, int* __restrict__ rowptr,
                            int* __restrict__ cursor) {
    __shared__ int sc[1024];
    int t = threadIdx.x;
    const int CH = 20;
    int base = t * CH;
    int s = 0;
    for (int i = 0; i < CH; i++) {
        int idx = base + i;
        if (idx < N_NODES) s += cnt[idx];
    }
    sc[t] = s;
    __syncthreads();
    for (int off = 1; off < 1024; off <<= 1) {
        int v = (t >= off) ? sc[t - off] : 0;
        __syncthreads();
        sc[t] += v;
        __syncthreads();
    }
    int run = sc[t] - s;
    for (int i = 0; i < CH; i++) {
        int idx = base + i;
        if (idx < N_NODES) {
            rowptr[idx] = run;
            cursor[idx] = run;
            run += cnt[idx];
        }
    }
    if (t == 1023) rowptr[N_NODES] = sc[1023];
}

__global__ void fill_kernel(const int* __restrict__ src, const int* __restrict__ dst,
                            int* __restrict__ cursor, int* __restrict__ esrc) {
    int e = blockIdx.x * 256 + threadIdx.x;
    if (e < N_EDGES) {
        int p = atomicAdd(&cursor[dst[e]], 1);
        esrc[p] = src[e];
    }
}

// ---------- GEMM: H[M,1024] = X[M,512] @ Wcat^T ; split stores H1/H2 bf16 ----------
// r7/r11-proven config (survivor of 5 structural challenges): 128x128 tile,
// BK=32, 256 threads (4 waves), TRIPLE-buffered LDS with counted vmcnt (T4).
// LDS swizzle (rule #21): slot' = slot ^ ((row>>1)&3) within each row's 64B
// line; staging source chunk = (l&3)^((l>>3)&3) keeps 64B-coalesced segments.
// DO NOT: raise min-waves (r5 spill), widen tile (r8 occupancy), load B
// per-lane from global (r9 uncoalesced), or column-slice agg (r12 L2 thrash).
__global__ __launch_bounds__(256, 4) void gemm_kernel(
    const unsigned short* __restrict__ A,      // [M_PAD][512] bf16
    const unsigned short* __restrict__ Wcat,   // [1024][512] bf16
    unsigned short* __restrict__ H1,           // [N_NODES][512]
    unsigned short* __restrict__ H2) {         // [N_NODES][512]
    __shared__ short Alds[3][128 * 32];
    __shared__ short Blds[3][128 * 32];
    int t = threadIdx.x;
    int wave = t >> 6, lane = t & 63;
    int s = blockIdx.x;
    int orig = (s & 7) * 157 + (s >> 3);       // bijective XCD swizzle (1256 = 8*157)
    int tm0 = (orig >> 3) * 128;
    int tn0 = (orig & 7) * 128;
    int wr = wave >> 1, wc = wave & 1;
    int lr = lane & 15, lg = lane >> 4;
    int q   = lane >> 2;                        // staging: row within 16-row group
    int cc  = (lane & 3) ^ ((lane >> 3) & 3);   // staging: global 16B-chunk (inv-swizzle)

    const unsigned short* Abase = A + (long)tm0 * D;
    const unsigned short* Bbase = Wcat + (long)tn0 * D;

    f32x4 acc[4][4];
#pragma unroll
    for (int i = 0; i < 4; i++)
#pragma unroll
        for (int j = 0; j < 4; j++) acc[i][j] = (f32x4){0.f, 0.f, 0.f, 0.f};

    auto stage = [&](int buf, int kt) {
        int kl = kt * 32;
#pragma unroll
        for (int i = 0; i < 2; i++) {
            int g = i * 4 + wave;              // 16-row group index 0..7
            __builtin_amdgcn_global_load_lds(
                (const __attribute__((address_space(1))) unsigned int*)(Abase + (long)(g * 16 + q) * D + kl + cc * 8),
                (__attribute__((address_space(3))) unsigned int*)&Alds[buf][g * 512],
                16, 0, 0);
            __builtin_amdgcn_global_load_lds(
                (const __attribute__((address_space(1))) unsigned int*)(Bbase + (long)(g * 16 + q) * D + kl + cc * 8),
                (__attribute__((address_space(3))) unsigned int*)&Blds[buf][g * 512],
                16, 0, 0);
        }
    };

    int swz = ((lr >> 1) & 3);   // read-side slot swizzle = (row>>1)&3 for fragment rows
    stage(0, 0);
    stage(1, 1);
    for (int kt = 0; kt < NT; ++kt) {
        // wait my stage(kt) retired: stage(kt+1) (4 loads) may remain in flight
        if (kt < NT - 1) asm volatile("s_waitcnt vmcnt(4)" ::: "memory");
        else             asm volatile("s_waitcnt vmcnt(0)" ::: "memory");
        __builtin_amdgcn_s_barrier();          // all waves: stage(kt) done, k-1 reads done
        __builtin_amdgcn_sched_barrier(0);     // no ds_read hoisting above the barrier
        if (kt + 2 < NT) stage((kt + 2) % 3, kt + 2);   // overwrites buf (kt-1)%3: safe

        int cur = kt % 3;
        bf16x8 af[4], wf[4];
#pragma unroll
        for (int i = 0; i < 4; i++)
            af[i] = *(const bf16x8*)&Alds[cur][(wr * 64 + i * 16 + lr) * 32 + (lg ^ swz) * 8];
#pragma unroll
        for (int j = 0; j < 4; j++)
            wf[j] = *(const bf16x8*)&Blds[cur][(wc * 64 + j * 16 + lr) * 32 + (lg ^ swz) * 8];
#pragma unroll
        for (int i = 0; i < 4; i++)
#pragma unroll
            for (int j = 0; j < 4; j++)
                acc[i][j] = __builtin_amdgcn_mfma_f32_16x16x32_bf16(af[i], wf[j], acc[i][j], 0, 0, 0);
    }

    // epilogue: split store (bias applied post-aggregation)
    bool hi = (tn0 >= 512);
    unsigned short* Hout = hi ? H2 : H1;
    int ncol0 = tn0 - (hi ? 512 : 0);
#pragma unroll
    for (int i = 0; i < 4; i++) {
        int mb = tm0 + wr * 64 + i * 16 + lg * 4;
#pragma unroll
        for (int j = 0; j < 4; j++) {
            int n = ncol0 + wc * 64 + j * 16 + lr;
#pragma unroll
            for (int r = 0; r < 4; r++) {
                int m = mb + r;
                if (m < N_NODES) Hout[(long)m * D + n] = f2bf(acc[i][j][r]);
            }
        }
    }
}

// ---------- fused aggregate + skip + bias (+relu): Y = agg(H1) + H2 + bias ----------
#define ACCUM(v)                                   \
    do {                                           \
        acc[0] += bflo((v).x); acc[1] += bfhi((v).x); \
        acc[2] += bflo((v).y); acc[3] += bfhi((v).y); \
        acc[4] += bflo((v).z); acc[5] += bfhi((v).z); \
        acc[6] += bflo((v).w); acc[7] += bfhi((v).w); \
    } while (0)

template <bool RELU, bool F32OUT>
__global__ void agg_kernel(const unsigned short* __restrict__ H1,
                           const unsigned short* __restrict__ H2,
                           const int* __restrict__ rowptr, const int* __restrict__ esrc,
                           const float* __restrict__ bias,
                           unsigned short* __restrict__ xn, float* __restrict__ fout) {
    int wave = threadIdx.x >> 6;
    int lane = threadIdx.x & 63;
    int n = blockIdx.x * 4 + wave;
    long cofs = lane * 8;
    if (n >= N_NODES) {
        if (!F32OUT && n < M_PAD)
            *(uint4*)(xn + (long)n * D + cofs) = make_uint4(0u, 0u, 0u, 0u);
        return;
    }
    int s = rowptr[n], e = rowptr[n + 1];
    uint4 h2 = *(const uint4*)(H2 + (long)n * D + cofs);
    float4 b0 = *(const float4*)(bias + cofs);
    float4 b1 = *(const float4*)(bias + cofs + 4);
    float acc[8] = {0.f, 0.f, 0.f, 0.f, 0.f, 0.f, 0.f, 0.f};
    int i = s;
    for (; i + 8 <= e; i += 8) {
        int s0 = esrc[i], s1 = esrc[i + 1], s2 = esrc[i + 2], s3 = esrc[i + 3];
        int s4 = esrc[i + 4], s5 = esrc[i + 5], s6 = esrc[i + 6], s7 = esrc[i + 7];
        uint4 v0 = *(const uint4*)(H1 + (long)s0 * D + cofs);
        uint4 v1 = *(const uint4*)(H1 + (long)s1 * D + cofs);
        uint4 v2 = *(const uint4*)(H1 + (long)s2 * D + cofs);
        uint4 v3 = *(const uint4*)(H1 + (long)s3 * D + cofs);
        uint4 v4 = *(const uint4*)(H1 + (long)s4 * D + cofs);
        uint4 v5 = *(const uint4*)(H1 + (long)s5 * D + cofs);
        uint4 v6 = *(const uint4*)(H1 + (long)s6 * D + cofs);
        uint4 v7 = *(const uint4*)(H1 + (long)s7 * D + cofs);
        ACCUM(v0); ACCUM(v1); ACCUM(v2); ACCUM(v3);
        ACCUM(v4); ACCUM(v5); ACCUM(v6); ACCUM(v7);
    }
    for (; i + 4 <= e; i += 4) {
        int s0 = esrc[i], s1 = esrc[i + 1], s2 = esrc[i + 2], s3 = esrc[i + 3];
        uint4 v0 = *(const uint4*)(H1 + (long)s0 * D + cofs);
        uint4 v1 = *(const uint4*)(H1 + (long)s1 * D + cofs);
        uint4 v2 = *(const uint4*)(H1 + (long)s2 * D + cofs);
        uint4 v3 = *(const uint4*)(H1 + (long)s3 * D + cofs);
        ACCUM(v0); ACCUM(v1); ACCUM(v2); ACCUM(v3);
    }
    for (; i < e; i++) {
        int sn = esrc[i];
        uint4 v = *(const uint4*)(H1 + (long)sn * D + cofs);
        ACCUM(v);
    }
    float o[8];
    o[0] = acc[0] + bflo(h2.x) + b0.x;
    o[1] = acc[1] + bfhi(h2.x) + b0.y;
    o[2] = acc[2] + bflo(h2.y) + b0.z;
    o[3] = acc[3] + bfhi(h2.y) + b0.w;
    o[4] = acc[4] + bflo(h2.z) + b1.x;
    o[5] = acc[5] + bfhi(h2.z) + b1.y;
    o[6] = acc[6] + bflo(h2.w) + b1.z;
    o[7] = acc[7] + bfhi(h2.w) + b1.w;
    if (RELU) {
#pragma unroll
        for (int k = 0; k < 8; k++) o[k] = o[k] > 0.f ? o[k] : 0.f;
    }
    if (F32OUT) {
        // non-temporal: d_out (40MB f32) is never re-read; don't evict H1 from L2.
        float* dst = fout + (long)n * D + cofs;
        f32x4 lo = {o[0], o[1], o[2], o[3]};
        f32x4 hi = {o[4], o[5], o[6], o[7]};
        __builtin_nontemporal_store(lo, (f32x4*)dst);
        __builtin_nontemporal_store(hi, (f32x4*)(dst + 4));
    } else {
        uint4 ov;
        ov.x = pack2(o[0], o[1]);
        ov.y = pack2(o[2], o[3]);
        ov.z = pack2(o[4], o[5]);
        ov.w = pack2(o[6], o[7]);
        *(uint4*)(xn + (long)n * D + cofs) = ov;
    }
}

extern "C" void kernel_launch(void* const* d_in, const int* in_sizes, int n_in,
                              void* d_out, int out_size, void* d_ws, size_t ws_size,
                              hipStream_t stream) {
    const float* x = (const float*)d_in[0];
    const int* ei = (const int*)d_in[1];
    const int* esrc_in = ei;             // row 0: src
    const int* edst_in = ei + N_EDGES;   // row 1: dst

    char* p = (char*)d_ws;
    size_t off = 0;
    auto alloc = [&](size_t bytes) -> char* {
        char* r = p + off;
        off = (off + bytes + 255) & ~(size_t)255;
        return r;
    };
    unsigned short* xA   = (unsigned short*)alloc((size_t)M_PAD * D * 2);
    unsigned short* xB   = (unsigned short*)alloc((size_t)M_PAD * D * 2);
    unsigned short* H1   = (unsigned short*)alloc((size_t)N_NODES * D * 2);
    unsigned short* H2   = (unsigned short*)alloc((size_t)N_NODES * D * 2);
    unsigned short* wcat = (unsigned short*)alloc((size_t)3 * 1024 * 512 * 2);
    float* biasb = (float*)alloc(3 * 512 * 4);
    int* cnt    = (int*)alloc(N_NODES * 4);
    int* rowptr = (int*)alloc((N_NODES + 1) * 4);
    int* cursor = (int*)alloc(N_NODES * 4);
    int* esrc   = (int*)alloc(N_EDGES * 4);

    prologue_kernel<<<CVT_BLOCKS + PREP_BLOCKS + ZERO_BLOCKS, 256, 0, stream>>>(
        x, xA,
        (const float*)d_in[2], (const float*)d_in[4], (const float*)d_in[5],
        (const float*)d_in[3], (const float*)d_in[6],
        (const float*)d_in[7], (const float*)d_in[9], (const float*)d_in[10],
        (const float*)d_in[8], (const float*)d_in[11],
        (const float*)d_in[12], (const float*)d_in[14], (const float*)d_in[15],
        (const float*)d_in[13], (const float*)d_in[16],
        wcat, biasb, cnt);
    count_kernel<<<(N_EDGES + 255) / 256, 256, 0, stream>>>(edst_in, cnt);
    scan_kernel<<<1, 1024, 0, stream>>>(cnt, rowptr, cursor);
    fill_kernel<<<(N_EDGES + 255) / 256, 256, 0, stream>>>(esrc_in, edst_in, cursor, esrc);

    unsigned short* xc = xA;
    unsigned short* xn = xB;
    for (int l = 0; l < 3; l++) {
        gemm_kernel<<<157 * 8, 256, 0, stream>>>(xc, wcat + (long)l * 1024 * 512, H1, H2);
        if (l < 2)
            agg_kernel<true, false><<<M_PAD / 4, 256, 0, stream>>>(H1, H2, rowptr, esrc,
                                                                   biasb + l * 512, xn, nullptr);
        else
            agg_kernel<false, true><<<(N_NODES + 3) / 4, 256, 0, stream>>>(
                H1, H2, rowptr, esrc, biasb + l * 512, nullptr, (float*)d_out);
        unsigned short* tmp = xc;
        xc = xn;
        xn = tmp;
    }
}